// Round 2
// baseline (110.151 us; speedup 1.0000x reference)
//
#include <hip/hip_runtime.h>
#include <math.h>

#define BB      32
#define H_KVN   8
#define GQ      4
#define H_QN    32
#define DD      128
#define KV_LENN 2048
#define PAGEN   16
#define PAGESN  128

// (1/sqrt(128)) * log2(e): compute softmax in exp2 domain -> single v_exp_f32
#define SCALE2  (0.08838834764831845f * 1.4426950408889634f)

// Kernel 1: split-K partial attention. grid = B * H_KV * nsplits, block = 256 (4 waves).
// Each wave owns positions p = start + waveid, step 4. One position per wave-iteration:
// 64 lanes x float2 = full 512B K row / V row, coalesced. 4 GQA head dots per row via
// 64-lane butterfly reduce. Online softmax (base-2). Waves merged via LDS, partial
// (o[4][128], m[4], l[4]) written to workspace.
__global__ __launch_bounds__(256)
void paged_decode_partial(const float* __restrict__ q,
                          const float* __restrict__ knew,
                          const float* __restrict__ vnew,
                          const float* __restrict__ kcache,
                          const float* __restrict__ vcache,
                          const int*   __restrict__ btab,
                          const int*   __restrict__ ctx_lens,
                          float*       __restrict__ ws_o,
                          float*       __restrict__ ws_ml,
                          int nsplits)
{
    const int bid = blockIdx.x;
    const int s  = bid % nsplits;
    const int h  = (bid / nsplits) % H_KVN;
    const int b  = bid / (nsplits * H_KVN);
    const int tid  = threadIdx.x;
    const int w    = tid >> 6;
    const int lane = tid & 63;

    const int ctx   = ctx_lens[b];
    const int chunk = (ctx + nsplits - 1) / nsplits;   // per-sequence balanced split
    const int start = s * chunk;
    const int end   = min(start + chunk, ctx);

    // q fragment: lane holds d = 2*lane, 2*lane+1 for the 4 grouped query heads
    float2 q2[GQ];
    const float* qb = q + ((size_t)b * H_QN + (size_t)h * GQ) * DD + 2 * lane;
    #pragma unroll
    for (int g = 0; g < GQ; ++g) q2[g] = *(const float2*)(qb + g * DD);

    float m[GQ], l[GQ];
    float2 o2[GQ];
    #pragma unroll
    for (int g = 0; g < GQ; ++g) { m[g] = -INFINITY; l[g] = 0.f; o2[g] = make_float2(0.f, 0.f); }

    const int* btb = btab + b * PAGESN;
    const float* knew_row = knew + ((size_t)b * H_KVN + h) * DD + 2 * lane;
    const float* vnew_row = vnew + ((size_t)b * H_KVN + h) * DD + 2 * lane;

    for (int p = start + w; p < end; p += 4) {
        const float *krow, *vrow;
        if (p == ctx - 1) {
            // new token lives in k/v (we must not scatter into the cache inputs)
            krow = knew_row; vrow = vnew_row;
        } else {
            const int slot = btb[p >> 4] * PAGEN + (p & (PAGEN - 1));
            const size_t off = ((size_t)slot * H_KVN + h) * DD + 2 * lane;
            krow = kcache + off; vrow = vcache + off;
        }
        const float2 kk = *(const float2*)krow;
        const float2 vv = *(const float2*)vrow;

        float dot[GQ];
        #pragma unroll
        for (int g = 0; g < GQ; ++g)
            dot[g] = q2[g].x * kk.x + q2[g].y * kk.y;
        #pragma unroll
        for (int msk = 32; msk >= 1; msk >>= 1) {
            #pragma unroll
            for (int g = 0; g < GQ; ++g)
                dot[g] += __shfl_xor(dot[g], msk);
        }
        #pragma unroll
        for (int g = 0; g < GQ; ++g) {
            const float sc = dot[g] * SCALE2;                 // base-2 domain
            const float nm = fmaxf(m[g], sc);
            const float corr = (m[g] == nm) ? 1.f : exp2f(m[g] - nm);  // -inf start -> 0
            const float pw = exp2f(sc - nm);
            l[g] = l[g] * corr + pw;
            m[g] = nm;
            o2[g].x = o2[g].x * corr + pw * vv.x;
            o2[g].y = o2[g].y * corr + pw * vv.y;
        }
    }

    // merge the 4 waves via LDS
    __shared__ float o_lds[4][GQ][DD];       // 8 KB
    __shared__ float m_lds[4][GQ];
    __shared__ float l_lds[4][GQ];
    #pragma unroll
    for (int g = 0; g < GQ; ++g) {
        o_lds[w][g][2 * lane]     = o2[g].x;
        o_lds[w][g][2 * lane + 1] = o2[g].y;
    }
    if (lane == 0) {
        #pragma unroll
        for (int g = 0; g < GQ; ++g) { m_lds[w][g] = m[g]; l_lds[w][g] = l[g]; }
    }
    __syncthreads();

    const size_t idx = (size_t)(b * H_KVN + h) * nsplits + s;
    float* op  = ws_o  + idx * (GQ * DD);
    float* mlp = ws_ml + idx * (GQ * 2);

    for (int e = tid; e < GQ * DD; e += 256) {
        const int g = e >> 7;
        const int d = e & (DD - 1);
        const float M = fmaxf(fmaxf(m_lds[0][g], m_lds[1][g]),
                              fmaxf(m_lds[2][g], m_lds[3][g]));
        float acc = 0.f;
        #pragma unroll
        for (int ww = 0; ww < 4; ++ww) {
            const float mw  = m_lds[ww][g];
            const float wgt = (mw == -INFINITY) ? 0.f : exp2f(mw - M);  // avoid inf-inf NaN
            acc += o_lds[ww][g][d] * wgt;
        }
        op[e] = acc;
    }
    if (tid < GQ) {
        const int g = tid;
        const float M = fmaxf(fmaxf(m_lds[0][g], m_lds[1][g]),
                              fmaxf(m_lds[2][g], m_lds[3][g]));
        float L = 0.f;
        #pragma unroll
        for (int ww = 0; ww < 4; ++ww) {
            const float mw  = m_lds[ww][g];
            const float wgt = (mw == -INFINITY) ? 0.f : exp2f(mw - M);
            L += l_lds[ww][g] * wgt;
        }
        mlp[g * 2]     = M;
        mlp[g * 2 + 1] = L;
    }
}

// Kernel 2: combine split partials and normalize. grid = B*H_KV, block = 256.
__global__ __launch_bounds__(256)
void paged_decode_reduce(const float* __restrict__ ws_o,
                         const float* __restrict__ ws_ml,
                         float*       __restrict__ out,
                         int nsplits)
{
    const int bh  = blockIdx.x;            // b*H_KV + h
    const int tid = threadIdx.x;
    __shared__ float ML[GQ][2];

    const float* mlp = ws_ml + (size_t)bh * nsplits * (GQ * 2);
    if (tid < GQ) {
        const int g = tid;
        float M = -INFINITY;
        for (int s = 0; s < nsplits; ++s)
            M = fmaxf(M, mlp[s * GQ * 2 + g * 2]);
        float L = 0.f;
        for (int s = 0; s < nsplits; ++s) {
            const float mw  = mlp[s * GQ * 2 + g * 2];
            const float wgt = (mw == -INFINITY) ? 0.f : exp2f(mw - M);
            L += mlp[s * GQ * 2 + g * 2 + 1] * wgt;
        }
        ML[g][0] = M;
        ML[g][1] = L;   // ctx >= 1 guarantees L > 0
    }
    __syncthreads();

    const float* op = ws_o + (size_t)bh * nsplits * (GQ * DD);
    const int b = bh / H_KVN, h = bh % H_KVN;
    float* outp = out + ((size_t)b * H_QN + (size_t)h * GQ) * DD;

    for (int e = tid; e < GQ * DD; e += 256) {
        const int g = e >> 7;
        const float M = ML[g][0], L = ML[g][1];
        float acc = 0.f;
        for (int s = 0; s < nsplits; ++s) {
            const float mw  = mlp[s * GQ * 2 + g * 2];
            const float wgt = (mw == -INFINITY) ? 0.f : exp2f(mw - M);
            acc += op[s * GQ * DD + e] * wgt;
        }
        outp[e] = acc / L;
    }
}

extern "C" void kernel_launch(void* const* d_in, const int* in_sizes, int n_in,
                              void* d_out, int out_size, void* d_ws, size_t ws_size,
                              hipStream_t stream) {
    const float* q  = (const float*)d_in[0];
    const float* k  = (const float*)d_in[1];
    const float* v  = (const float*)d_in[2];
    const float* kc = (const float*)d_in[3];
    const float* vc = (const float*)d_in[4];
    // d_in[5] slot_mapping: unused — derived from block_tables + context_lens
    const int* bt   = (const int*)d_in[6];
    const int* ctx  = (const int*)d_in[7];
    float* out = (float*)d_out;

    // pick split count from available workspace (deterministic: ws_size is fixed)
    const size_t per_split = (size_t)BB * H_KVN * (GQ * DD + GQ * 2) * sizeof(float);
    int nsplits = (int)(ws_size / per_split);
    if (nsplits > 8) nsplits = 8;
    if (nsplits < 1) nsplits = 1;

    float* ws_o  = (float*)d_ws;
    float* ws_ml = ws_o + (size_t)BB * H_KVN * nsplits * (GQ * DD);

    paged_decode_partial<<<BB * H_KVN * nsplits, 256, 0, stream>>>(
        q, k, v, kc, vc, bt, ctx, ws_o, ws_ml, nsplits);
    paged_decode_reduce<<<BB * H_KVN, 256, 0, stream>>>(ws_o, ws_ml, out, nsplits);
}

// Round 3
// 74.964 us; speedup vs baseline: 1.4694x; 1.4694x over previous
//
#include <hip/hip_runtime.h>
#include <math.h>

#define BB      32
#define H_KVN   8
#define GQ      4
#define H_QN    32
#define DD      128
#define KV_LENN 2048
#define PAGEN   16
#define PAGESN  128
#define NSPLIT_MAX 16

// (1/sqrt(128)) * log2(e): softmax in exp2 domain -> single v_exp_f32
#define SCALE2  (0.08838834764831845f * 1.4426950408889634f)

// Kernel 1: split-K partial attention. grid = B*H_KV*nsplits, block = 256 (4 waves).
// Each 16-lane group owns ONE position; lane l16 owns d = l16*8..l16*8+8 (16*8 = 128).
// A wave covers 4 consecutive positions per iteration; the 4 waves of a block cover 16
// consecutive positions (= one page) per block-iteration. Dot reduce = 4 shfl_xor steps
// within the 16-lane group (4 DS ops/position vs 24 for a 64-lane butterfly).
__global__ __launch_bounds__(256)
void paged_decode_partial(const float* __restrict__ q,
                          const float* __restrict__ knew,
                          const float* __restrict__ vnew,
                          const float* __restrict__ kcache,
                          const float* __restrict__ vcache,
                          const int*   __restrict__ btab,
                          const int*   __restrict__ ctx_lens,
                          float*       __restrict__ ws_o,
                          float*       __restrict__ ws_ml,
                          int nsplits)
{
    const int bid = blockIdx.x;
    const int s  = bid % nsplits;
    const int h  = (bid / nsplits) % H_KVN;
    const int b  = bid / (nsplits * H_KVN);
    const int tid  = threadIdx.x;
    const int w    = tid >> 6;          // wave 0..3
    const int lane = tid & 63;
    const int g16  = lane >> 4;         // position sub-index within wave (0..3)
    const int l16  = lane & 15;         // d-slice owner: d = l16*8 .. +8

    const int ctx = ctx_lens[b];
    // chunk: per-sequence balanced, rounded up to 16 so a block walks whole pages
    const int chunk = (((ctx + nsplits - 1) / nsplits) + 15) & ~15;
    const int start = s * chunk;
    const int end   = min(start + chunk, ctx);

    // q fragments: 4 grouped heads x 8 floats at d = l16*8
    float4 qa[GQ], qb4[GQ];
    {
        const float* qp = q + ((size_t)b * H_QN + (size_t)h * GQ) * DD + l16 * 8;
        #pragma unroll
        for (int g = 0; g < GQ; ++g) {
            qa[g]  = *(const float4*)(qp + g * DD);
            qb4[g] = *(const float4*)(qp + g * DD + 4);
        }
    }

    float m[GQ], l[GQ];
    float o[GQ][8];
    #pragma unroll
    for (int g = 0; g < GQ; ++g) {
        m[g] = -INFINITY; l[g] = 0.f;
        #pragma unroll
        for (int j = 0; j < 8; ++j) o[g][j] = 0.f;
    }

    const int* btb = btab + b * PAGESN;
    const float* knew_row = knew + ((size_t)b * H_KVN + h) * DD + l16 * 8;
    const float* vnew_row = vnew + ((size_t)b * H_KVN + h) * DD + l16 * 8;

    for (int p0 = start + w * 4; p0 < end; p0 += 16) {
        const int p = p0 + g16;          // this 16-lane group's position
        if (p < end) {
            const float *krow, *vrow;
            if (p == ctx - 1) {
                krow = knew_row; vrow = vnew_row;   // new token: never written to cache
            } else {
                const int slot = btb[p >> 4] * PAGEN + (p & (PAGEN - 1));
                const size_t off = ((size_t)slot * H_KVN + h) * DD + l16 * 8;
                krow = kcache + off; vrow = vcache + off;
            }
            const float4 ka = *(const float4*)(krow);
            const float4 kb = *(const float4*)(krow + 4);
            const float4 va = *(const float4*)(vrow);
            const float4 vb = *(const float4*)(vrow + 4);

            float dot[GQ];
            #pragma unroll
            for (int g = 0; g < GQ; ++g) {
                float d0 = qa[g].x * ka.x + qa[g].y * ka.y + qa[g].z * ka.z + qa[g].w * ka.w;
                d0 += qb4[g].x * kb.x + qb4[g].y * kb.y + qb4[g].z * kb.z + qb4[g].w * kb.w;
                dot[g] = d0;
            }
            // reduce across the 16-lane group
            #pragma unroll
            for (int msk = 8; msk >= 1; msk >>= 1) {
                #pragma unroll
                for (int g = 0; g < GQ; ++g)
                    dot[g] += __shfl_xor(dot[g], msk);
            }
            const float vvv[8] = { va.x, va.y, va.z, va.w, vb.x, vb.y, vb.z, vb.w };
            #pragma unroll
            for (int g = 0; g < GQ; ++g) {
                const float sc   = dot[g] * SCALE2;            // base-2 domain
                const float nm   = fmaxf(m[g], sc);
                const float corr = exp2f(m[g] - nm);           // m=-inf first -> 0
                const float pw   = exp2f(sc - nm);
                l[g] = l[g] * corr + pw;
                m[g] = nm;
                #pragma unroll
                for (int j = 0; j < 8; ++j)
                    o[g][j] = o[g][j] * corr + pw * vvv[j];
            }
        }
    }

    // merge the 4 groups of this wave (lane^16, lane^32); d-layout identical per group
    #pragma unroll
    for (int msk = 16; msk <= 32; msk <<= 1) {
        #pragma unroll
        for (int g = 0; g < GQ; ++g) {
            const float mo = __shfl_xor(m[g], msk);
            const float lo = __shfl_xor(l[g], msk);
            const float M  = fmaxf(m[g], mo);
            const float c1 = (m[g] == -INFINITY) ? 0.f : exp2f(m[g] - M);
            const float c2 = (mo   == -INFINITY) ? 0.f : exp2f(mo   - M);
            l[g] = l[g] * c1 + lo * c2;
            #pragma unroll
            for (int j = 0; j < 8; ++j) {
                const float oo = __shfl_xor(o[g][j], msk);
                o[g][j] = o[g][j] * c1 + oo * c2;
            }
            m[g] = M;
        }
    }

    // merge the 4 waves via LDS
    __shared__ float o_lds[4][GQ][DD];       // 8 KB
    __shared__ float m_lds[4][GQ];
    __shared__ float l_lds[4][GQ];
    if (g16 == 0) {
        #pragma unroll
        for (int g = 0; g < GQ; ++g)
            #pragma unroll
            for (int j = 0; j < 8; ++j)
                o_lds[w][g][l16 * 8 + j] = o[g][j];
    }
    if (lane == 0) {
        #pragma unroll
        for (int g = 0; g < GQ; ++g) { m_lds[w][g] = m[g]; l_lds[w][g] = l[g]; }
    }
    __syncthreads();

    const size_t idx = (size_t)(b * H_KVN + h) * nsplits + s;
    float* op  = ws_o  + idx * (GQ * DD);
    float* mlp = ws_ml + idx * (GQ * 2);

    for (int e = tid; e < GQ * DD; e += 256) {
        const int g = e >> 7;
        const int d = e & (DD - 1);
        const float M = fmaxf(fmaxf(m_lds[0][g], m_lds[1][g]),
                              fmaxf(m_lds[2][g], m_lds[3][g]));
        float acc = 0.f;
        #pragma unroll
        for (int ww = 0; ww < 4; ++ww) {
            const float mw  = m_lds[ww][g];
            const float wgt = (mw == -INFINITY) ? 0.f : exp2f(mw - M);  // avoid inf-inf NaN
            acc += o_lds[ww][g][d] * wgt;
        }
        op[e] = acc;
    }
    if (tid < GQ) {
        const int g = tid;
        const float M = fmaxf(fmaxf(m_lds[0][g], m_lds[1][g]),
                              fmaxf(m_lds[2][g], m_lds[3][g]));
        float L = 0.f;
        #pragma unroll
        for (int ww = 0; ww < 4; ++ww) {
            const float mw  = m_lds[ww][g];
            const float wgt = (mw == -INFINITY) ? 0.f : exp2f(mw - M);
            L += l_lds[ww][g] * wgt;
        }
        mlp[g * 2]     = M;
        mlp[g * 2 + 1] = L;
    }
}

// Kernel 2: combine split partials and normalize. grid = B*H_KV, block = 256.
__global__ __launch_bounds__(256)
void paged_decode_reduce(const float* __restrict__ ws_o,
                         const float* __restrict__ ws_ml,
                         float*       __restrict__ out,
                         int nsplits)
{
    const int bh  = blockIdx.x;            // b*H_KV + h
    const int tid = threadIdx.x;
    __shared__ float ML[GQ][2];

    const float* mlp = ws_ml + (size_t)bh * nsplits * (GQ * 2);
    if (tid < GQ) {
        const int g = tid;
        float M = -INFINITY;
        for (int s = 0; s < nsplits; ++s)
            M = fmaxf(M, mlp[s * GQ * 2 + g * 2]);
        float L = 0.f;
        for (int s = 0; s < nsplits; ++s) {
            const float mw  = mlp[s * GQ * 2 + g * 2];
            const float wgt = (mw == -INFINITY) ? 0.f : exp2f(mw - M);
            L += mlp[s * GQ * 2 + g * 2 + 1] * wgt;
        }
        ML[g][0] = M;
        ML[g][1] = L;   // ctx >= 1 guarantees L > 0
    }
    __syncthreads();

    const float* op = ws_o + (size_t)bh * nsplits * (GQ * DD);
    const int b = bh / H_KVN, h = bh % H_KVN;
    float* outp = out + ((size_t)b * H_QN + (size_t)h * GQ) * DD;

    for (int e = tid; e < GQ * DD; e += 256) {
        const int g = e >> 7;
        const float M = ML[g][0], L = ML[g][1];
        float acc = 0.f;
        for (int s = 0; s < nsplits; ++s) {
            const float mw  = mlp[s * GQ * 2 + g * 2];
            const float wgt = (mw == -INFINITY) ? 0.f : exp2f(mw - M);
            acc += op[s * GQ * DD + e] * wgt;
        }
        outp[e] = acc / L;
    }
}

extern "C" void kernel_launch(void* const* d_in, const int* in_sizes, int n_in,
                              void* d_out, int out_size, void* d_ws, size_t ws_size,
                              hipStream_t stream) {
    const float* q  = (const float*)d_in[0];
    const float* k  = (const float*)d_in[1];
    const float* v  = (const float*)d_in[2];
    const float* kc = (const float*)d_in[3];
    const float* vc = (const float*)d_in[4];
    // d_in[5] slot_mapping: unused — derived from block_tables + context_lens
    const int* bt   = (const int*)d_in[6];
    const int* ctx  = (const int*)d_in[7];
    float* out = (float*)d_out;

    // pick split count from available workspace (deterministic: ws_size is fixed)
    const size_t per_split = (size_t)BB * H_KVN * (GQ * DD + GQ * 2) * sizeof(float);
    int nsplits = (int)(ws_size / per_split);
    if (nsplits > NSPLIT_MAX) nsplits = NSPLIT_MAX;
    if (nsplits < 1) nsplits = 1;

    float* ws_o  = (float*)d_ws;
    float* ws_ml = ws_o + (size_t)BB * H_KVN * nsplits * (GQ * DD);

    paged_decode_partial<<<BB * H_KVN * nsplits, 256, 0, stream>>>(
        q, k, v, kc, vc, bt, ctx, ws_o, ws_ml, nsplits);
    paged_decode_reduce<<<BB * H_KVN, 256, 0, stream>>>(ws_o, ws_ml, out, nsplits);
}